// Round 4
// baseline (236.206 us; speedup 1.0000x reference)
//
#include <hip/hip_runtime.h>
#include <hip/hip_bf16.h>
#include <stdint.h>

#define NN 51200
#define FF 400
#define HH 256
#define CC 2
#define EE 819200
#define GG 128
#define NEG 0.01f
#define NKT 13          // ceil(400/32) K-tiles of 32
#define PAD 64          // padded neighbor slots per node
#define NCH 8           // channel chunks
#define CCH 32          // channels per chunk (chunk = 3.25 MB, fits 4MB XCD L2)

typedef unsigned int u32;
typedef unsigned short u16;
typedef __attribute__((ext_vector_type(8))) short s8;    // 8 bf16
typedef __attribute__((ext_vector_type(8))) u16 us8;     // 8 ushort indices
typedef __attribute__((ext_vector_type(4))) float f4;    // MFMA acc

__device__ __forceinline__ short f2bf(float f) {
    __hip_bfloat16 b = __float2bfloat16(f);
    return *reinterpret_cast<short*>(&b);
}
__device__ __forceinline__ float bflo(u32 x) { return __uint_as_float(x << 16); }
__device__ __forceinline__ float bfhi(u32 x) { return __uint_as_float(x & 0xffff0000u); }

// Order-preserving float<->uint encoding for atomicMax on floats.
__device__ __forceinline__ u32 encf(float f) {
    u32 u = __float_as_uint(f);
    return (u & 0x80000000u) ? ~u : (u | 0x80000000u);
}
__device__ __forceinline__ float decf(u32 e) {
    return (e & 0x80000000u) ? __uint_as_float(e & 0x7fffffffu)
                             : __uint_as_float(~e);
}

// ---- pack W[400][256] f32 -> wp[kt][nt][lane][8] bf16 fragment layout ----
__global__ void k_pack_w(const float* __restrict__ W, short* __restrict__ wp) {
    int t = blockIdx.x * 256 + threadIdx.x;        // (kt*16+nt)*64+l
    if (t >= NKT * 16 * 64) return;
    int l = t & 63;
    int k0 = (t >> 10) * 32 + ((l >> 4) * 8);
    int col = ((t >> 6) & 15) * 16 + (l & 15);
    s8 v;
    #pragma unroll
    for (int j = 0; j < 8; ++j) {
        int k = k0 + j;
        v[j] = f2bf((k < FF) ? W[(size_t)k * HH + col] : 0.f);
    }
    *(s8*)(wp + (size_t)t * 8) = v;
}

// ---- ELL fill: cnt[col]++ and csr_pad[col*PAD + pos] = row (ushort) ----
__global__ void k_fill(const int* __restrict__ row, const int* __restrict__ col,
                       int* __restrict__ cnt, u16* __restrict__ csr) {
    int i0 = (blockIdx.x * blockDim.x + threadIdx.x) * 4;
    int4 c = *(const int4*)(col + i0);
    int4 r = *(const int4*)(row + i0);
    int p;
    p = atomicAdd(&cnt[c.x], 1); if (p < PAD) csr[(size_t)c.x * PAD + p] = (u16)r.x;
    p = atomicAdd(&cnt[c.y], 1); if (p < PAD) csr[(size_t)c.y * PAD + p] = (u16)r.y;
    p = atomicAdd(&cnt[c.z], 1); if (p < PAD) csr[(size_t)c.z * PAD + p] = (u16)r.z;
    p = atomicAdd(&cnt[c.w], 1); if (p < PAD) csr[(size_t)c.w * PAD + p] = (u16)r.w;
}

// ---- MFMA GEMM: ht[chunk][N][32] = rsqrt(deg+1) * (x[N,F] @ W), bf16 ----
// Tile M=64 x N=256; 4 waves, wave w owns cols [w*64, w*64+64).
__global__ __launch_bounds__(256) void k_mfma(
        const float* __restrict__ x, const short* __restrict__ wp,
        const int* __restrict__ cnt, short* __restrict__ ht)
{
    const int tid = threadIdx.x;
    const int l = tid & 63;
    const int w = tid >> 6;
    const int bm = blockIdx.x * 64;
    const int arow = bm + (l & 15);
    const int kl = (l >> 4) * 8;
    const s8* wb = (const s8*)wp;

    f4 acc[4][4] = {};
    for (int kt = 0; kt < NKT; ++kt) {
        const int k0 = kt * 32 + kl;
        s8 a[4];
        if (k0 < FF) {
            #pragma unroll
            for (int mi = 0; mi < 4; ++mi) {
                const float* p = x + (size_t)(arow + mi * 16) * FF + k0;
                float4 v0 = *(const float4*)p;
                float4 v1 = *(const float4*)(p + 4);
                a[mi][0] = f2bf(v0.x); a[mi][1] = f2bf(v0.y);
                a[mi][2] = f2bf(v0.z); a[mi][3] = f2bf(v0.w);
                a[mi][4] = f2bf(v1.x); a[mi][5] = f2bf(v1.y);
                a[mi][6] = f2bf(v1.z); a[mi][7] = f2bf(v1.w);
            }
        } else {
            #pragma unroll
            for (int mi = 0; mi < 4; ++mi)
                #pragma unroll
                for (int j = 0; j < 8; ++j) a[mi][j] = 0;
        }
        s8 b[4];
        #pragma unroll
        for (int ni = 0; ni < 4; ++ni)
            b[ni] = wb[(size_t)(kt * 16 + w * 4 + ni) * 64 + l];
        #pragma unroll
        for (int mi = 0; mi < 4; ++mi)
            #pragma unroll
            for (int ni = 0; ni < 4; ++ni)
                acc[mi][ni] = __builtin_amdgcn_mfma_f32_16x16x32_bf16(
                    a[mi], b[ni], acc[mi][ni], 0, 0, 0);
    }
    #pragma unroll
    for (int mi = 0; mi < 4; ++mi) {
        #pragma unroll
        for (int r = 0; r < 4; ++r) {
            const int rowg = bm + mi * 16 + (l >> 4) * 4 + r;
            const float dn = rsqrtf((float)(cnt[rowg] + 1));
            #pragma unroll
            for (int ni = 0; ni < 4; ++ni) {
                const int chunk = w * 2 + (ni >> 1);
                const int off = (ni & 1) * 16 + (l & 15);
                ht[((size_t)chunk * NN + rowg) * CCH + off] =
                    f2bf(dn * acc[mi][ni][r]);
            }
        }
    }
}

// ---- gather + LeakyReLU + fused segment-max pool, chunk-resident in L2 ----
// grid (NN/256, NCH); block 256 = 32 groups of 8 lanes; group handles 8
// consecutive nodes, lane covers 4 channels (short4 = 8B -> 64B line/group).
__global__ __launch_bounds__(256) void k_gather(
        const short* __restrict__ ht, const int* __restrict__ cnt,
        const u16* __restrict__ csr, const int* __restrict__ batch,
        const float* __restrict__ bg, u32* __restrict__ penc)
{
    const int t = threadIdx.x;
    const int g = t >> 3, li = t & 7;
    const int chunk = blockIdx.y;
    const short* hc = ht + (size_t)chunk * NN * CCH;
    const int ch0 = chunk * CCH + li * 4;
    const float4 bias = *(const float4*)(bg + ch0);

    float m0 = 0.f, m1 = 0.f, m2 = 0.f, m3 = 0.f;
    int runb = -1;
    for (int m = 0; m < 8; ++m) {
        const int n = blockIdx.x * 256 + g * 8 + m;
        const int degt = cnt[n];
        const int deg = (degt < PAD) ? degt : PAD;
        const float dn = rsqrtf((float)(degt + 1));
        const u16* cp = csr + (size_t)n * PAD;
        uint2 sv = *(const uint2*)(hc + (size_t)n * CCH + li * 4);
        float a0 = bflo(sv.x), a1 = bfhi(sv.x);
        float a2 = bflo(sv.y), a3 = bfhi(sv.y);
        int wmax = deg;                               // wave-uniform bound
        wmax = max(wmax, __shfl_xor(wmax, 8, 64));
        wmax = max(wmax, __shfl_xor(wmax, 16, 64));
        wmax = max(wmax, __shfl_xor(wmax, 32, 64));
        for (int j0 = 0; j0 < wmax; j0 += 8) {
            us8 iv = *(const us8*)(cp + j0);
            #pragma unroll
            for (int k = 0; k < 8; ++k) {
                uint2 v = *(const uint2*)(hc + (size_t)iv[k] * CCH + li * 4);
                const bool p = (j0 + k) < deg;
                u32 vx = p ? v.x : 0u, vy = p ? v.y : 0u;
                a0 += bflo(vx); a1 += bfhi(vx);
                a2 += bflo(vy); a3 += bfhi(vy);
            }
        }
        float v0 = dn * a0 + bias.x; v0 = (v0 >= 0.f) ? v0 : NEG * v0;
        float v1 = dn * a1 + bias.y; v1 = (v1 >= 0.f) ? v1 : NEG * v1;
        float v2 = dn * a2 + bias.z; v2 = (v2 >= 0.f) ? v2 : NEG * v2;
        float v3 = dn * a3 + bias.w; v3 = (v3 >= 0.f) ? v3 : NEG * v3;
        const int b = batch[n];
        if (b != runb) {
            if (runb >= 0) {
                u32* p = penc + runb * HH + ch0;
                atomicMax(p + 0, encf(m0)); atomicMax(p + 1, encf(m1));
                atomicMax(p + 2, encf(m2)); atomicMax(p + 3, encf(m3));
            }
            runb = b; m0 = v0; m1 = v1; m2 = v2; m3 = v3;
        } else {
            m0 = fmaxf(m0, v0); m1 = fmaxf(m1, v1);
            m2 = fmaxf(m2, v2); m3 = fmaxf(m3, v3);
        }
    }
    u32* p = penc + runb * HH + ch0;
    atomicMax(p + 0, encf(m0)); atomicMax(p + 1, encf(m1));
    atomicMax(p + 2, encf(m2)); atomicMax(p + 3, encf(m3));
}

// ---- decode pool + write pool out + logits, one block per graph ----
__global__ __launch_bounds__(256) void k_out(
        const u32* __restrict__ penc, const float* __restrict__ Wl,
        const float* __restrict__ bl, float* __restrict__ out)
{
    __shared__ float r0[4], r1[4];
    const int g = blockIdx.x, t = threadIdx.x;
    float v = decf(penc[g * HH + t]);
    out[GG * CC + g * HH + t] = v;
    float s0 = v * Wl[t * CC + 0];
    float s1 = v * Wl[t * CC + 1];
    #pragma unroll
    for (int off = 32; off >= 1; off >>= 1) {
        s0 += __shfl_down(s0, off, 64);
        s1 += __shfl_down(s1, off, 64);
    }
    if ((t & 63) == 0) { r0[t >> 6] = s0; r1[t >> 6] = s1; }
    __syncthreads();
    if (t == 0) {
        out[g * CC + 0] = r0[0] + r0[1] + r0[2] + r0[3] + bl[0];
        out[g * CC + 1] = r1[0] + r1[1] + r1[2] + r1[3] + bl[1];
    }
}

extern "C" void kernel_launch(void* const* d_in, const int* in_sizes, int n_in,
                              void* d_out, int out_size, void* d_ws, size_t ws_size,
                              hipStream_t stream)
{
    const float* x    = (const float*)d_in[0];
    const int*   ei   = (const int*)d_in[1];
    const int*   batch= (const int*)d_in[2];
    const float* Wg   = (const float*)d_in[3];
    const float* bg   = (const float*)d_in[4];
    const float* Wl   = (const float*)d_in[5];
    const float* bl   = (const float*)d_in[6];
    float* out = (float*)d_out;
    const int* row = ei;        // sources
    const int* col = ei + EE;   // targets

    size_t o = 0;
    char* wsb = (char*)d_ws;
    auto take = [&](size_t b) { void* p = wsb + o; o += (b + 255) & ~(size_t)255; return p; };
    short* ht   = (short*)take((size_t)NCH * NN * CCH * 2);           // 26.2 MB
    int*   cnt  = (int*)take((size_t)NN * 4);                         // 204800 B
    u32*   penc = (u32*)take((size_t)GG * HH * 4);                    // after cnt
    u16*   csr  = (u16*)take((size_t)NN * PAD * 2);                   // 6.55 MB
    short* wp   = (short*)take((size_t)NKT * 16 * 64 * 8 * 2);        // 213 KB

    // one memset zeroes cnt AND penc (adjacent; cnt size is 256-aligned)
    hipMemsetAsync(cnt, 0, (size_t)NN * 4 + (size_t)GG * HH * 4, stream);

    k_fill<<<EE / 1024, 256, 0, stream>>>(row, col, cnt, csr);
    k_pack_w<<<(NKT * 16 * 64 + 255) / 256, 256, 0, stream>>>(Wg, wp);
    k_mfma<<<NN / 64, 256, 0, stream>>>(x, wp, cnt, ht);
    k_gather<<<dim3(NN / 256, NCH), 256, 0, stream>>>(ht, cnt, csr, batch, bg, penc);
    k_out<<<GG, 256, 0, stream>>>(penc, Wl, bl, out);
}

// Round 5
// 170.416 us; speedup vs baseline: 1.3861x; 1.3861x over previous
//
#include <hip/hip_runtime.h>
#include <hip/hip_bf16.h>
#include <stdint.h>

#define NN 51200
#define FF 400
#define HH 256
#define CC 2
#define EE 819200
#define GG 128
#define NEG 0.01f
#define NKT 13          // ceil(400/32) K-tiles of 32
#define PAD 64          // padded neighbor slots per node
#define NBK 200         // dst buckets = dst>>8 (51200/256)
#define EB  4096        // edges per block in sort passes (EE/200)

typedef unsigned int u32;
typedef unsigned short u16;
typedef __attribute__((ext_vector_type(8))) short s8;    // 8 bf16
typedef __attribute__((ext_vector_type(8))) u16 us8;     // 8 ushort indices
typedef __attribute__((ext_vector_type(4))) float f4;    // MFMA acc

__device__ __forceinline__ short f2bf(float f) {
    __hip_bfloat16 b = __float2bfloat16(f);
    return *reinterpret_cast<short*>(&b);
}
__device__ __forceinline__ float bf2f(short s) {
    u32 u = ((u32)(u16)s) << 16;
    return __uint_as_float(u);
}
// Order-preserving float<->uint encoding for atomicMax on floats.
__device__ __forceinline__ u32 encf(float f) {
    u32 u = __float_as_uint(f);
    return (u & 0x80000000u) ? ~u : (u | 0x80000000u);
}
__device__ __forceinline__ float decf(u32 e) {
    return (e & 0x80000000u) ? __uint_as_float(e & 0x7fffffffu)
                             : __uint_as_float(~e);
}

// ---- pack W[400][256] f32 -> wp[kt][nt][lane][8] bf16 fragment layout ----
__global__ void k_pack_w(const float* __restrict__ W, short* __restrict__ wp) {
    int t = blockIdx.x * 256 + threadIdx.x;        // (kt*16+nt)*64+l
    if (t >= NKT * 16 * 64) return;
    int l = t & 63;
    int k0 = (t >> 10) * 32 + ((l >> 4) * 8);
    int col = ((t >> 6) & 15) * 16 + (l & 15);
    s8 v;
    #pragma unroll
    for (int j = 0; j < 8; ++j) {
        int k = k0 + j;
        v[j] = f2bf((k < FF) ? W[(size_t)k * HH + col] : 0.f);
    }
    *(s8*)(wp + (size_t)t * 8) = v;
}

// ==== bucketed counting-sort CSR build (atomic-light, replaces k_fill) ====

// pass 1: global bucket histogram via LDS-reduced atomics (40K global atomics)
__global__ __launch_bounds__(256) void k_hist2(const int* __restrict__ col,
                                               int* __restrict__ bcnt) {
    __shared__ int sh[NBK];
    const int t = threadIdx.x;
    if (t < NBK) sh[t] = 0;
    __syncthreads();
    const int base = blockIdx.x * EB;
    for (int i = t; i < EB; i += 256)
        atomicAdd(&sh[col[base + i] >> 8], 1);
    __syncthreads();
    if (t < NBK && sh[t]) atomicAdd(&bcnt[t], sh[t]);
}

// pass 2: exclusive scan of 200 bucket counts -> bbase, init cursor
__global__ __launch_bounds__(256) void k_scan2(const int* __restrict__ bcnt,
                                               int* __restrict__ bbase,
                                               int* __restrict__ cursor) {
    __shared__ int v[256];
    const int t = threadIdx.x;
    int mine = (t < NBK) ? bcnt[t] : 0;
    v[t] = mine;
    __syncthreads();
    for (int d = 1; d < 256; d <<= 1) {
        int x = (t >= d) ? v[t - d] : 0;
        __syncthreads();
        v[t] += x;
        __syncthreads();
    }
    if (t < NBK) { int e = v[t] - mine; bbase[t] = e; cursor[t] = e; }
}

// pass 3: place packed edges into bucket-contiguous ebuf
__global__ __launch_bounds__(256) void k_place(const int* __restrict__ row,
                                               const int* __restrict__ col,
                                               int* __restrict__ cursor,
                                               u32* __restrict__ ebuf) {
    __shared__ int lcnt[NBK], lbase[NBK];
    const int t = threadIdx.x;
    if (t < NBK) lcnt[t] = 0;
    __syncthreads();
    const int base = blockIdx.x * EB;
    for (int i = t; i < EB; i += 256)
        atomicAdd(&lcnt[col[base + i] >> 8], 1);
    __syncthreads();
    if (t < NBK) {
        int c = lcnt[t];
        if (c) lbase[t] = atomicAdd(&cursor[t], c);   // one global atomic/bucket
        lcnt[t] = 0;                                  // reuse as local cursor
    }
    __syncthreads();
    for (int i = t; i < EB; i += 256) {
        int d = col[base + i], s = row[base + i];
        int b = d >> 8;
        int lp = atomicAdd(&lcnt[b], 1);
        ebuf[lbase[b] + lp] = ((u32)s << 8) | (u32)(d & 255);
    }
}

// pass 4: one block per bucket: build 256-node ELL slice in LDS, write coalesced
__global__ __launch_bounds__(256) void k_b2(const u32* __restrict__ ebuf,
                                            const int* __restrict__ bcnt,
                                            const int* __restrict__ bbase,
                                            int* __restrict__ cnt,
                                            u16* __restrict__ csr) {
    __shared__ u16 ell[256 * PAD];     // 32 KB
    __shared__ int h[256];
    const int t = threadIdx.x;
    const int b = blockIdx.x;
    int* elli = (int*)ell;
    for (int i = t; i < 256 * PAD / 2; i += 256) elli[i] = 0;
    h[t] = 0;
    __syncthreads();
    const int cb = bcnt[b], ba = bbase[b];
    for (int i = t; i < cb; i += 256) {
        u32 v = ebuf[ba + i];
        int dl = v & 255;
        int s = (int)(v >> 8);
        int p = atomicAdd(&h[dl], 1);
        if (p < PAD) ell[dl * PAD + p] = (u16)s;
    }
    __syncthreads();
    const int n0 = b << 8;
    cnt[n0 + t] = h[t];
    uint4* dst = (uint4*)(csr + (size_t)n0 * PAD);
    const uint4* src = (const uint4*)ell;
    for (int i = t; i < 256 * PAD * 2 / 16; i += 256) dst[i] = src[i];
}

// ---- MFMA GEMM: h'[N,H] = rsqrt(deg+1) * (x[N,F] @ W), bf16 out ----
// Tile M=64 x N=256; 4 waves, wave w owns cols [w*64, w*64+64).
__global__ __launch_bounds__(256) void k_mfma(
        const float* __restrict__ x, const short* __restrict__ wp,
        const int* __restrict__ cnt, __hip_bfloat16* __restrict__ h)
{
    const int tid = threadIdx.x;
    const int l = tid & 63;
    const int w = tid >> 6;
    const int bm = blockIdx.x * 64;
    const int arow = bm + (l & 15);
    const int kl = (l >> 4) * 8;
    const s8* wb = (const s8*)wp;

    f4 acc[4][4] = {};
    for (int kt = 0; kt < NKT; ++kt) {
        const int k0 = kt * 32 + kl;
        s8 a[4];
        if (k0 < FF) {
            #pragma unroll
            for (int mi = 0; mi < 4; ++mi) {
                const float* p = x + (size_t)(arow + mi * 16) * FF + k0;
                float4 v0 = *(const float4*)p;
                float4 v1 = *(const float4*)(p + 4);
                a[mi][0] = f2bf(v0.x); a[mi][1] = f2bf(v0.y);
                a[mi][2] = f2bf(v0.z); a[mi][3] = f2bf(v0.w);
                a[mi][4] = f2bf(v1.x); a[mi][5] = f2bf(v1.y);
                a[mi][6] = f2bf(v1.z); a[mi][7] = f2bf(v1.w);
            }
        } else {
            #pragma unroll
            for (int mi = 0; mi < 4; ++mi)
                #pragma unroll
                for (int j = 0; j < 8; ++j) a[mi][j] = 0;
        }
        s8 b[4];
        #pragma unroll
        for (int ni = 0; ni < 4; ++ni)
            b[ni] = wb[(size_t)(kt * 16 + w * 4 + ni) * 64 + l];
        #pragma unroll
        for (int mi = 0; mi < 4; ++mi)
            #pragma unroll
            for (int ni = 0; ni < 4; ++ni)
                acc[mi][ni] = __builtin_amdgcn_mfma_f32_16x16x32_bf16(
                    a[mi], b[ni], acc[mi][ni], 0, 0, 0);
    }
    #pragma unroll
    for (int mi = 0; mi < 4; ++mi) {
        #pragma unroll
        for (int r = 0; r < 4; ++r) {
            const int rowg = bm + mi * 16 + (l >> 4) * 4 + r;
            const float dn = rsqrtf((float)(cnt[rowg] + 1));
            const size_t base = (size_t)rowg * HH + w * 64 + (l & 15);
            #pragma unroll
            for (int ni = 0; ni < 4; ++ni)
                h[base + ni * 16] = __float2bfloat16(dn * acc[mi][ni][r]);
        }
    }
}

// ---- gather + LeakyReLU + fused segment-max pool (proven R3 structure) ----
// 256 threads = 4 waves; wave = node slot (4 channels/thread, short4 row loads).
__global__ __launch_bounds__(256) void k_gather(
        const __hip_bfloat16* __restrict__ h, const int* __restrict__ cnt,
        const u16* __restrict__ csr, const int* __restrict__ batch,
        const float* __restrict__ bg, u32* __restrict__ penc)
{
    __shared__ float4 sv[256];
    __shared__ int sb[256];
    const int t = threadIdx.x;
    const int l = t & 63;
    const int slot = t >> 6;
    const int c4 = l * 4;
    const float4 bias = *(const float4*)(bg + c4);
    const short* hs = (const short*)h;

    float m0 = 0.f, m1 = 0.f, m2 = 0.f, m3 = 0.f;
    int runb = -1;
    for (int m = 0; m < 4; ++m) {
        const int n = blockIdx.x * 16 + m * 4 + slot;
        const int degt = cnt[n];
        const int deg = (degt < PAD) ? degt : PAD;
        const float dn = rsqrtf((float)(degt + 1));
        short4 sself = *(const short4*)(hs + (size_t)n * HH + c4);
        float a0 = bf2f(sself.x), a1 = bf2f(sself.y);
        float a2 = bf2f(sself.z), a3 = bf2f(sself.w);
        const u16* cp = csr + (size_t)n * PAD;
        for (int j0 = 0; j0 < deg; j0 += 8) {
            us8 iv = *(const us8*)(cp + j0);
            #pragma unroll
            for (int k = 0; k < 8; ++k) {
                u32 ui = (u32)iv[k];
                ui = (ui < (u32)NN) ? ui : (u32)(NN - 1);
                short4 v = *(const short4*)(hs + (size_t)ui * HH + c4);
                if (j0 + k < deg) {           // wave-uniform predicate
                    a0 += bf2f(v.x); a1 += bf2f(v.y);
                    a2 += bf2f(v.z); a3 += bf2f(v.w);
                }
            }
        }
        float v0 = dn * a0 + bias.x; v0 = (v0 >= 0.f) ? v0 : NEG * v0;
        float v1 = dn * a1 + bias.y; v1 = (v1 >= 0.f) ? v1 : NEG * v1;
        float v2 = dn * a2 + bias.z; v2 = (v2 >= 0.f) ? v2 : NEG * v2;
        float v3 = dn * a3 + bias.w; v3 = (v3 >= 0.f) ? v3 : NEG * v3;
        const int b = batch[n];
        if (b != runb) {
            if (runb >= 0) {
                u32* p = penc + runb * HH + c4;
                atomicMax(p + 0, encf(m0)); atomicMax(p + 1, encf(m1));
                atomicMax(p + 2, encf(m2)); atomicMax(p + 3, encf(m3));
            }
            runb = b; m0 = v0; m1 = v1; m2 = v2; m3 = v3;
        } else {
            m0 = fmaxf(m0, v0); m1 = fmaxf(m1, v1);
            m2 = fmaxf(m2, v2); m3 = fmaxf(m3, v3);
        }
    }
    // cross-slot merge of the final run (block is usually one graph)
    sv[t] = make_float4(m0, m1, m2, m3);
    sb[t] = runb;
    __syncthreads();
    const int b0 = sb[l], b1 = sb[l + 64], b2 = sb[l + 128], b3 = sb[l + 192];
    const bool allsame = (b0 == b1) && (b0 == b2) && (b0 == b3);
    if (allsame) {
        if (slot == 0) {
            float4 x0 = sv[l], x1 = sv[l + 64], x2 = sv[l + 128], x3 = sv[l + 192];
            u32* p = penc + b0 * HH + c4;
            atomicMax(p + 0, encf(fmaxf(fmaxf(x0.x, x1.x), fmaxf(x2.x, x3.x))));
            atomicMax(p + 1, encf(fmaxf(fmaxf(x0.y, x1.y), fmaxf(x2.y, x3.y))));
            atomicMax(p + 2, encf(fmaxf(fmaxf(x0.z, x1.z), fmaxf(x2.z, x3.z))));
            atomicMax(p + 3, encf(fmaxf(fmaxf(x0.w, x1.w), fmaxf(x2.w, x3.w))));
        }
    } else {
        u32* p = penc + runb * HH + c4;
        atomicMax(p + 0, encf(m0)); atomicMax(p + 1, encf(m1));
        atomicMax(p + 2, encf(m2)); atomicMax(p + 3, encf(m3));
    }
}

// ---- decode pool + write pool out + logits, one block per graph ----
__global__ __launch_bounds__(256) void k_out(
        const u32* __restrict__ penc, const float* __restrict__ Wl,
        const float* __restrict__ bl, float* __restrict__ out)
{
    __shared__ float r0[4], r1[4];
    const int g = blockIdx.x, t = threadIdx.x;
    float v = decf(penc[g * HH + t]);
    out[GG * CC + g * HH + t] = v;
    float s0 = v * Wl[t * CC + 0];
    float s1 = v * Wl[t * CC + 1];
    #pragma unroll
    for (int off = 32; off >= 1; off >>= 1) {
        s0 += __shfl_down(s0, off, 64);
        s1 += __shfl_down(s1, off, 64);
    }
    if ((t & 63) == 0) { r0[t >> 6] = s0; r1[t >> 6] = s1; }
    __syncthreads();
    if (t == 0) {
        out[g * CC + 0] = r0[0] + r0[1] + r0[2] + r0[3] + bl[0];
        out[g * CC + 1] = r1[0] + r1[1] + r1[2] + r1[3] + bl[1];
    }
}

extern "C" void kernel_launch(void* const* d_in, const int* in_sizes, int n_in,
                              void* d_out, int out_size, void* d_ws, size_t ws_size,
                              hipStream_t stream)
{
    const float* x    = (const float*)d_in[0];
    const int*   ei   = (const int*)d_in[1];
    const int*   batch= (const int*)d_in[2];
    const float* Wg   = (const float*)d_in[3];
    const float* bg   = (const float*)d_in[4];
    const float* Wl   = (const float*)d_in[5];
    const float* bl   = (const float*)d_in[6];
    float* out = (float*)d_out;
    const int* row = ei;        // sources
    const int* col = ei + EE;   // targets

    size_t o = 0;
    char* wsb = (char*)d_ws;
    auto take = [&](size_t b) { void* p = wsb + o; o += (b + 255) & ~(size_t)255; return p; };
    __hip_bfloat16* h = (__hip_bfloat16*)take((size_t)NN * HH * 2);   // 26.2 MB
    int*   bcnt = (int*)take((size_t)NBK * 4);                        // 800 B ->256-pad
    u32*   penc = (u32*)take((size_t)GG * HH * 4);                    // adjacent
    int*   bbase= (int*)take((size_t)NBK * 4);
    int*   cursor=(int*)take((size_t)NBK * 4);
    int*   cnt  = (int*)take((size_t)NN * 4);
    u16*   csr  = (u16*)take((size_t)NN * PAD * 2);                   // 6.55 MB
    u32*   ebuf = (u32*)take((size_t)EE * 4);                         // 3.28 MB
    short* wp   = (short*)take((size_t)NKT * 16 * 64 * 8 * 2);        // 213 KB

    // one memset zeroes bcnt AND penc (adjacent, bcnt 256B-aligned slot)
    hipMemsetAsync(bcnt, 0, 1024 + (size_t)GG * HH * 4, stream);

    k_hist2<<<NBK, 256, 0, stream>>>(col, bcnt);
    k_scan2<<<1, 256, 0, stream>>>(bcnt, bbase, cursor);
    k_place<<<NBK, 256, 0, stream>>>(row, col, cursor, ebuf);
    k_b2<<<NBK, 256, 0, stream>>>(ebuf, bcnt, bbase, cnt, csr);
    k_pack_w<<<(NKT * 16 * 64 + 255) / 256, 256, 0, stream>>>(Wg, wp);
    k_mfma<<<NN / 64, 256, 0, stream>>>(x, wp, cnt, h);
    k_gather<<<NN / 16, 256, 0, stream>>>(h, cnt, csr, batch, bg, penc);
    k_out<<<GG, 256, 0, stream>>>(penc, Wl, bl, out);
}